// Round 12
// baseline (400.900 us; speedup 1.0000x reference)
//
#include <hip/hip_runtime.h>
#include <cstdint>

#define DEVI __device__ __forceinline__

typedef __bf16 bf16x8_t __attribute__((ext_vector_type(8)));
typedef float f32x4_t __attribute__((ext_vector_type(4)));

typedef const __attribute__((address_space(1))) unsigned int* gas_t;
typedef __attribute__((address_space(3))) unsigned int* las_t;

// async global->LDS, 16B per lane, dst = wave-uniform base (+lane*16 by HW)
DEVI void glds16(const void* g, void* l) {
  __builtin_amdgcn_global_load_lds((gas_t)g, (las_t)l, 16, 0, 0);
}

DEVI uint16_t f2b(float f) {  // fp32 -> bf16 RNE
  uint32_t u = __builtin_bit_cast(uint32_t, f);
  u += 0x7fffu + ((u >> 16) & 1u);
  return (uint16_t)(u >> 16);
}

// opaque LDS b128 read: invisible to SIInsertWaitcnts => no auto vmcnt(0)
// drain against in-flight global_load_lds. Caller MUST wait lgkmcnt +
// sched_barrier(0) before consuming (rule 18).
template <int IMM>
DEVI f32x4_t ldsr(uint32_t addr) {
  f32x4_t r;
  if constexpr (IMM == 0)
    asm volatile("ds_read_b128 %0, %1" : "=v"(r) : "v"(addr));
  else if constexpr (IMM == 1024)
    asm volatile("ds_read_b128 %0, %1 offset:1024" : "=v"(r) : "v"(addr));
  else if constexpr (IMM == 2048)
    asm volatile("ds_read_b128 %0, %1 offset:2048" : "=v"(r) : "v"(addr));
  else
    asm volatile("ds_read_b128 %0, %1 offset:3072" : "=v"(r) : "v"(addr));
  return r;
}

// meta layout (ints): [0..7] counts, [8..16] offsets(9), [17..24] fill,
// [25] nTiles128, [32..103] tileExpert, [104..175] tilePos0, [176..247] tileValidEnd
static constexpr int MAXT = 72;

// ---------------- gate body: logits + top2 + softmax + x->bf16 --------------
DEVI void gate_body(int bid, const float* __restrict__ x,
                    const float* __restrict__ Wg, const float* __restrict__ bg,
                    int* __restrict__ gidx, float* __restrict__ gw,
                    uint16_t* __restrict__ xb) {
  const int lane = threadIdx.x & 63;
  const int b = bid * 4 + (threadIdx.x >> 6);
  float acc[8];
#pragma unroll
  for (int e = 0; e < 8; ++e) acc[e] = 0.f;
  const float* xr = x + (size_t)b * 1024;
  uint16_t* xbr = xb + (size_t)b * 1024;
#pragma unroll
  for (int it = 0; it < 4; ++it) {
    const int d0 = it * 256 + lane * 4;
    float4 xv = *(const float4*)(xr + d0);
    uint64_t pk = (uint64_t)f2b(xv.x) | ((uint64_t)f2b(xv.y) << 16) |
                  ((uint64_t)f2b(xv.z) << 32) | ((uint64_t)f2b(xv.w) << 48);
    *(uint64_t*)(xbr + d0) = pk;
    float xs[4] = {xv.x, xv.y, xv.z, xv.w};
#pragma unroll
    for (int q = 0; q < 4; ++q) {
      const float4* wrow = (const float4*)(Wg + (size_t)(d0 + q) * 8);
      float4 wa = wrow[0], wb = wrow[1];
      acc[0] += xs[q] * wa.x; acc[1] += xs[q] * wa.y;
      acc[2] += xs[q] * wa.z; acc[3] += xs[q] * wa.w;
      acc[4] += xs[q] * wb.x; acc[5] += xs[q] * wb.y;
      acc[6] += xs[q] * wb.z; acc[7] += xs[q] * wb.w;
    }
  }
#pragma unroll
  for (int off = 32; off; off >>= 1)
#pragma unroll
    for (int e = 0; e < 8; ++e) acc[e] += __shfl_xor(acc[e], off, 64);
  if (lane == 0) {
    float l[8];
#pragma unroll
    for (int e = 0; e < 8; ++e) l[e] = acc[e] + bg[e];
    int i0 = 0;
#pragma unroll
    for (int e = 1; e < 8; ++e) if (l[e] > l[i0]) i0 = e;   // strict > : matches top_k tie rule
    int i1 = (i0 == 0) ? 1 : 0;
#pragma unroll
    for (int e = 0; e < 8; ++e) if (e != i0 && l[e] > l[i1]) i1 = e;
    float ex = expf(l[i1] - l[i0]);
    float s = 1.f + ex;
    gidx[2 * b] = i0; gidx[2 * b + 1] = i1;
    gw[2 * b] = 1.f / s; gw[2 * b + 1] = ex / s;
  }
}

// ---------------- transpose body: [E][K][N] fp32 -> [E][N][K] bf16 ----------
DEVI void transpose_body(const float* __restrict__ in, uint16_t* __restrict__ outp,
                         int K, int N, int e, int k0, int n0,
                         uint16_t (*t)[72]) {
  const int r = threadIdx.x >> 2;          // 0..63
  const int c0 = (threadIdx.x & 3) * 16;   // 0,16,32,48
  const float* src = in + ((size_t)e * K + k0 + r) * N + n0 + c0;
#pragma unroll
  for (int q = 0; q < 4; ++q) {
    float4 v = *(const float4*)(src + q * 4);
    uint64_t pk = (uint64_t)f2b(v.x) | ((uint64_t)f2b(v.y) << 16) |
                  ((uint64_t)f2b(v.z) << 32) | ((uint64_t)f2b(v.w) << 48);
    *(uint64_t*)&t[r][c0 + q * 4] = pk;
  }
  __syncthreads();
  alignas(16) uint16_t buf[16];
#pragma unroll
  for (int j = 0; j < 16; ++j) buf[j] = t[c0 + j][r];
  uint16_t* dst = outp + ((size_t)e * N + n0 + r) * K + k0 + c0;
  *(uint4*)dst = *(const uint4*)&buf[0];
  *(uint4*)(dst + 8) = *(const uint4*)&buf[8];
}

// ---------------- M1: gate (blocks 0..1023) || transpose W1 (1024..9215) ----
__global__ __launch_bounds__(256) void moe_m1(const float* __restrict__ x,
    const float* __restrict__ Wg, const float* __restrict__ bg,
    int* __restrict__ gidx, float* __restrict__ gw, uint16_t* __restrict__ xb,
    const float* __restrict__ W1, uint16_t* __restrict__ w1t) {
  __shared__ uint16_t t[64][72];
  const int bid = blockIdx.x;
  if (bid < 1024) {
    gate_body(bid, x, Wg, bg, gidx, gw, xb);
  } else {
    int tt = bid - 1024;                     // 8192 tiles: e(8) x kb(16) x nb(64)
    int e = tt >> 10, rem = tt & 1023;
    int kb = rem >> 6, nb2 = rem & 63;
    transpose_body(W1, w1t, 1024, 4096, e, kb * 64, nb2 * 64, t);
  }
}

// ---------------- scan+scatter fused (1 block) ------------------------------
__global__ __launch_bounds__(256) void moe_scan2(const int* __restrict__ gidx,
    const float* __restrict__ gw, int* __restrict__ meta,
    int* __restrict__ row_index, float* __restrict__ row_w) {
  __shared__ int cnt[8];
  __shared__ int offs[8];
  __shared__ int fill[8];
  if (threadIdx.x < 8) { cnt[threadIdx.x] = 0; fill[threadIdx.x] = 0; }
  __syncthreads();
  int loc[8] = {0, 0, 0, 0, 0, 0, 0, 0};
  for (int i = threadIdx.x; i < 8192; i += 256) {
    int e = gidx[i];
#pragma unroll
    for (int q = 0; q < 8; ++q) loc[q] += (e == q) ? 1 : 0;
  }
#pragma unroll
  for (int q = 0; q < 8; ++q) if (loc[q]) atomicAdd(&cnt[q], loc[q]);
  __syncthreads();
  if (threadIdx.x == 0) {
    int off = 0, tIdx = 0;
    for (int e = 0; e < 8; ++e) {
      int c = cnt[e];
      meta[e] = c;
      meta[8 + e] = off;
      offs[e] = off;
      int nt = (c + 127) >> 7;
      for (int mt = 0; mt < nt; ++mt) {
        meta[32 + tIdx] = e;
        meta[104 + tIdx] = off + mt * 128;
        meta[176 + tIdx] = off + c;
        ++tIdx;
      }
      off += c;
    }
    meta[16] = off;
    meta[25] = tIdx;
  }
  __syncthreads();
  for (int i = threadIdx.x; i < 8192; i += 256) {
    int e = gidx[i];
    int pos = offs[e] + atomicAdd(&fill[e], 1);
    row_index[pos] = i >> 1;
    row_w[pos] = gw[i];
  }
}

// ---------------- GEMM core r12: r3 tile + counted 2-slot pipeline ----------
// 128x128 tile, BK=32, 4 waves, 4 blocks/CU (32KB LDS, 128-reg cap fits
// 60 VGPR + 64 AGPR = 124, no spill). Per iter: stage(t+1) (4 glds16) ->
// vmcnt(4) [completes stage(t), issued one full iteration ago; stage(t+1)
// stays in flight with a full iteration of cover] -> s_barrier -> 8 opaque
// ds_read_b128 -> lgkmcnt(0)+sched_barrier -> setprio(1) 16 MFMA setprio(0)
// -> s_barrier [reads done before next overwrite].
// Swizzle (verified 0-conflict): LDS slot (row,ci) holds global k-chunk
// ci^((row>>1)&3); read slot term lane-invariant across frags.
// MODE 1: h[pos] = relu(gather(x)[pos] @ W1t[e]^T + b1[e]), ND=4096, KD=1024
// MODE 2: out[rix[pos]] += rw[pos]*(h[pos] @ W2t[e]^T + b2[e]), ND=1024, KD=4096
template <int KD, int ND, int MODE>
DEVI void gemm_core(int wg, const uint16_t* __restrict__ Am,
                    const uint16_t* __restrict__ Bt, const float* __restrict__ bias,
                    const int* __restrict__ meta, const int* __restrict__ row_index,
                    const float* __restrict__ row_w, uint16_t* __restrict__ hout,
                    float* __restrict__ out, uint16_t (*As)[4096], uint16_t (*Bs)[4096]) {
  constexpr int NB = ND / 128;
  constexpr int NIT = KD / 32;
  const int nb = wg % NB;
  const int ty = wg / NB;
  if (ty >= meta[25]) return;
  const int e = meta[32 + ty];
  const int pos0 = meta[104 + ty];
  const int vend = meta[176 + ty];

  const int tid = threadIdx.x;
  const int lane = tid & 63;
  const int w = tid >> 6;
  const int wr = w >> 1, wc = w & 1;

  size_t aoff[2], boff[2];
#pragma unroll
  for (int j = 0; j < 2; ++j) {
    int c = j * 256 + tid;
    int row = c >> 2;
    int skc = (c & 3) ^ ((row >> 1) & 3);
    int pos = pos0 + row;
    if (pos > 8191) pos = 8191;
    int ar = (MODE == 1) ? row_index[pos] : pos;
    aoff[j] = ((size_t)ar * KD + (size_t)skc * 8) * 2;
    boff[j] = (((size_t)e * ND + (size_t)nb * 128 + row) * KD + (size_t)skc * 8) * 2;
  }
  const char* Ag = (const char*)Am;
  const char* Bg = (const char*)Bt;

  auto stage = [&](int s, int kt) {
#pragma unroll
    for (int j = 0; j < 2; ++j) {
      glds16(Ag + aoff[j] + (size_t)kt * 64, &As[s][(j * 256 + w * 64) * 8]);
      glds16(Bg + boff[j] + (size_t)kt * 64, &Bs[s][(j * 256 + w * 64) * 8]);
    }
  };

  f32x4_t acc[4][4];
  f32x4_t z;
  z[0] = 0.f; z[1] = 0.f; z[2] = 0.f; z[3] = 0.f;
#pragma unroll
  for (int m = 0; m < 4; ++m)
#pragma unroll
    for (int n = 0; n < 4; ++n) acc[m][n] = z;

  // frag read byte bases (swizzle term lane-invariant across m/n: row>>1&3
  // depends only on (lane&15)>>1 since wr*64, wc*64, m*16 are ==0 mod 8)
  const uint32_t skcf = (uint32_t)(((lane >> 4) ^ ((lane & 15) >> 1)) & 3);
  const uint32_t aB0 = (uint32_t)(size_t)&As[0][0] +
                       (uint32_t)((wr * 64 + (lane & 15)) * 64) + skcf * 16;
  const uint32_t bB0 = (uint32_t)(size_t)&Bs[0][0] +
                       (uint32_t)((wc * 64 + (lane & 15)) * 64) + skcf * 16;

  stage(0, 0);
  for (int t = 0; t < NIT; ++t) {
    int tc = t + 1; if (tc > NIT - 1) tc = NIT - 1;  // tail dup, count-preserving
    stage((t + 1) & 1, tc);
    // completes stage(t) (issued one full iteration ago); stage(t+1) stays
    // in flight with one full iteration of latency cover
    asm volatile("s_waitcnt vmcnt(4)" ::: "memory");
    __builtin_amdgcn_s_barrier();

    const uint32_t aA = aB0 + (uint32_t)((t & 1) * 8192);
    const uint32_t bA = bB0 + (uint32_t)((t & 1) * 8192);
    f32x4_t av[4], bv[4];
    av[0] = ldsr<0>(aA); av[1] = ldsr<1024>(aA);
    av[2] = ldsr<2048>(aA); av[3] = ldsr<3072>(aA);
    bv[0] = ldsr<0>(bA); bv[1] = ldsr<1024>(bA);
    bv[2] = ldsr<2048>(bA); bv[3] = ldsr<3072>(bA);
    asm volatile("s_waitcnt lgkmcnt(0)" ::: "memory");
    __builtin_amdgcn_sched_barrier(0);

    __builtin_amdgcn_s_setprio(1);
#pragma unroll
    for (int m = 0; m < 4; ++m)
#pragma unroll
      for (int n = 0; n < 4; ++n)
        acc[m][n] = __builtin_amdgcn_mfma_f32_16x16x32_bf16(
            __builtin_bit_cast(bf16x8_t, av[m]), __builtin_bit_cast(bf16x8_t, bv[n]),
            acc[m][n], 0, 0, 0);
    __builtin_amdgcn_s_setprio(0);
    __builtin_amdgcn_s_barrier();   // reads of slot t done before next stage issue
  }
  asm volatile("s_waitcnt vmcnt(0)" ::: "memory");  // drain before exit

  // epilogue: C/D mapping col=lane&15, row=(lane>>4)*4+i
  const int cb = nb * 128 + wc * 64;
  if constexpr (MODE == 1) {
#pragma unroll
    for (int m = 0; m < 4; ++m) {
      int pr = pos0 + wr * 64 + m * 16 + ((lane >> 4) << 2);
#pragma unroll
      for (int i = 0; i < 4; ++i) {
        int pos = pr + i;
        if (pos < vend) {
#pragma unroll
          for (int n = 0; n < 4; ++n) {
            int col = cb + n * 16 + (lane & 15);
            float v = acc[m][n][i] + bias[e * ND + col];
            v = fmaxf(v, 0.f);
            hout[(size_t)pos * ND + col] = f2b(v);
          }
        }
      }
    }
  } else {
#pragma unroll
    for (int m = 0; m < 4; ++m) {
      int pr = pos0 + wr * 64 + m * 16 + ((lane >> 4) << 2);
#pragma unroll
      for (int i = 0; i < 4; ++i) {
        int pos = pr + i;
        if (pos < vend) {
          int bi = row_index[pos];
          float wgt = row_w[pos];
          float* orow = out + (size_t)bi * ND;
#pragma unroll
          for (int n = 0; n < 4; ++n) {
            int col = cb + n * 16 + (lane & 15);
            float v = (acc[m][n][i] + bias[e * ND + col]) * wgt;
            atomicAdd(orow + col, v);
          }
        }
      }
    }
  }
}

// ---------------- M2: GEMM1 (blocks 0..2303) || transpose W2 (2304..10495) --
__global__ __launch_bounds__(256, 4) void moe_m2(const uint16_t* __restrict__ xb,
    const uint16_t* __restrict__ w1t, const float* __restrict__ b1,
    const int* __restrict__ meta, const int* __restrict__ rix,
    const float* __restrict__ rw, uint16_t* __restrict__ h,
    const float* __restrict__ W2, uint16_t* __restrict__ w2t) {
  __shared__ uint16_t As[2][4096];
  __shared__ uint16_t Bs[2][4096];
  const int bid = blockIdx.x;
  if (bid < 2304) {
    // bijective XCD swizzle over the GEMM sub-grid (2304 % 8 == 0)
    constexpr int NWG = 2304;
    constexpr int Q8 = NWG >> 3;  // 288
    int wg = (bid & 7) * Q8 + (bid >> 3);
    gemm_core<1024, 4096, 1>(wg, xb, w1t, b1, meta, rix, rw, h, nullptr, As, Bs);
  } else {
    int tt = bid - 2304;                    // 8192 tiles: e(8) x kb(64) x nb(16)
    int e = tt >> 10, rem = tt & 1023;
    int kb = rem >> 4, nb2 = rem & 15;
    transpose_body(W2, w2t, 4096, 1024, e, kb * 64, nb2 * 64,
                   (uint16_t(*)[72]) & As[0][0]);
  }
}

// ---------------- GEMM2 standalone ------------------------------------------
__global__ __launch_bounds__(256, 4) void moe_gemm2(const uint16_t* __restrict__ h,
    const uint16_t* __restrict__ w2t, const float* __restrict__ b2,
    const int* __restrict__ meta, const int* __restrict__ rix,
    const float* __restrict__ rw, float* __restrict__ out) {
  __shared__ uint16_t As[2][4096];
  __shared__ uint16_t Bs[2][4096];
  const int nwg = gridDim.x;
  const int orig = blockIdx.x;
  const int q8 = nwg >> 3, r8 = nwg & 7, xcd = orig & 7, loc = orig >> 3;
  int wg = (xcd < r8 ? xcd * (q8 + 1) : r8 * (q8 + 1) + (xcd - r8) * q8) + loc;
  gemm_core<4096, 1024, 2>(wg, h, w2t, b2, meta, rix, rw, nullptr, out, As, Bs);
}

extern "C" void kernel_launch(void* const* d_in, const int* in_sizes, int n_in,
                              void* d_out, int out_size, void* d_ws, size_t ws_size,
                              hipStream_t stream) {
  const float* x  = (const float*)d_in[0];   // [4096,1024]
  const float* Wg = (const float*)d_in[1];   // [1024,8]
  const float* bg = (const float*)d_in[2];   // [8]
  const float* W1 = (const float*)d_in[3];   // [8,1024,4096]
  const float* b1 = (const float*)d_in[4];   // [8,4096]
  const float* W2 = (const float*)d_in[5];   // [8,4096,1024]
  const float* b2 = (const float*)d_in[6];   // [8,1024]
  float* out = (float*)d_out;                // [4096,1024]

  char* ws = (char*)d_ws;
  uint16_t* w1t = (uint16_t*)ws; ws += (size_t)8 * 4096 * 1024 * 2;  // [E][H][D] bf16
  uint16_t* w2t = (uint16_t*)ws; ws += (size_t)8 * 1024 * 4096 * 2;  // [E][O][H] bf16
  uint16_t* xb  = (uint16_t*)ws; ws += (size_t)4096 * 1024 * 2;      // [B][D] bf16
  uint16_t* h   = (uint16_t*)ws; ws += (size_t)8192 * 4096 * 2;      // [8192][H] bf16
  int*   gidx = (int*)ws;   ws += 8192 * 4;
  float* gw   = (float*)ws; ws += 8192 * 4;
  int*   rix  = (int*)ws;   ws += 8192 * 4;
  float* rw   = (float*)ws; ws += 8192 * 4;
  int*   meta = (int*)ws;   ws += 4096;

  hipMemsetAsync(d_out, 0, (size_t)4096 * 1024 * 4, stream);
  // M1: gate (1024) || transpose W1 (8192)
  moe_m1<<<dim3(1024 + 8192), 256, 0, stream>>>(x, Wg, bg, gidx, gw, xb, W1, w1t);
  // fused scan + scatter (single block)
  moe_scan2<<<dim3(1), 256, 0, stream>>>(gidx, gw, meta, rix, rw);
  // M2: GEMM1 (2304) || transpose W2 (8192)
  moe_m2<<<dim3(2304 + 8192), 256, 0, stream>>>(xb, w1t, b1, meta, rix, rw, h, W2, w2t);
  // GEMM2: 8 nb * 72 ty = 576
  moe_gemm2<<<dim3(8 * MAXT), 256, 0, stream>>>(h, w2t, b2, meta, rix, rw, out);
}

// Round 13
// 389.898 us; speedup vs baseline: 1.0282x; 1.0282x over previous
//
#include <hip/hip_runtime.h>
#include <cstdint>

#define DEVI __device__ __forceinline__

typedef __bf16 bf16x8_t __attribute__((ext_vector_type(8)));
typedef float f32x4_t __attribute__((ext_vector_type(4)));

typedef const __attribute__((address_space(1))) unsigned int* gas_t;
typedef __attribute__((address_space(3))) unsigned int* las_t;

// async global->LDS, 16B per lane, dst = wave-uniform base (+lane*16 by HW)
DEVI void glds16(const void* g, void* l) {
  __builtin_amdgcn_global_load_lds((gas_t)g, (las_t)l, 16, 0, 0);
}

DEVI uint16_t f2b(float f) {  // fp32 -> bf16 RNE
  uint32_t u = __builtin_bit_cast(uint32_t, f);
  u += 0x7fffu + ((u >> 16) & 1u);
  return (uint16_t)(u >> 16);
}

// meta layout (ints): [0..7] counts, [8..16] offsets(9), [17..24] fill,
// [25] nTiles128, [32..103] tileExpert, [104..175] tilePos0, [176..247] tileValidEnd
static constexpr int MAXT = 72;

// ---------------- gate: logits + top2 + softmax + x->bf16 (fused cvt) -------
__global__ __launch_bounds__(256) void moe_gate(const float* __restrict__ x,
    const float* __restrict__ Wg, const float* __restrict__ bg,
    int* __restrict__ gidx, float* __restrict__ gw, uint16_t* __restrict__ xb) {
  const int lane = threadIdx.x & 63;
  const int b = blockIdx.x * 4 + (threadIdx.x >> 6);
  float acc[8];
#pragma unroll
  for (int e = 0; e < 8; ++e) acc[e] = 0.f;
  const float* xr = x + (size_t)b * 1024;
  uint16_t* xbr = xb + (size_t)b * 1024;
#pragma unroll
  for (int it = 0; it < 4; ++it) {
    const int d0 = it * 256 + lane * 4;
    float4 xv = *(const float4*)(xr + d0);
    uint64_t pk = (uint64_t)f2b(xv.x) | ((uint64_t)f2b(xv.y) << 16) |
                  ((uint64_t)f2b(xv.z) << 32) | ((uint64_t)f2b(xv.w) << 48);
    *(uint64_t*)(xbr + d0) = pk;
    float xs[4] = {xv.x, xv.y, xv.z, xv.w};
#pragma unroll
    for (int q = 0; q < 4; ++q) {
      const float4* wrow = (const float4*)(Wg + (size_t)(d0 + q) * 8);
      float4 wa = wrow[0], wb = wrow[1];
      acc[0] += xs[q] * wa.x; acc[1] += xs[q] * wa.y;
      acc[2] += xs[q] * wa.z; acc[3] += xs[q] * wa.w;
      acc[4] += xs[q] * wb.x; acc[5] += xs[q] * wb.y;
      acc[6] += xs[q] * wb.z; acc[7] += xs[q] * wb.w;
    }
  }
#pragma unroll
  for (int off = 32; off; off >>= 1)
#pragma unroll
    for (int e = 0; e < 8; ++e) acc[e] += __shfl_xor(acc[e], off, 64);
  if (lane == 0) {
    float l[8];
#pragma unroll
    for (int e = 0; e < 8; ++e) l[e] = acc[e] + bg[e];
    int i0 = 0;
#pragma unroll
    for (int e = 1; e < 8; ++e) if (l[e] > l[i0]) i0 = e;   // strict > : matches top_k tie rule
    int i1 = (i0 == 0) ? 1 : 0;
#pragma unroll
    for (int e = 0; e < 8; ++e) if (e != i0 && l[e] > l[i1]) i1 = e;
    float ex = expf(l[i1] - l[i0]);
    float s = 1.f + ex;
    gidx[2 * b] = i0; gidx[2 * b + 1] = i1;
    gw[2 * b] = 1.f / s; gw[2 * b + 1] = ex / s;
  }
}

// ---------------- transpose body: [E][K][N] fp32 -> [E][N][K] bf16 ----------
DEVI void transpose_body(const float* __restrict__ in, uint16_t* __restrict__ outp,
                         int K, int N, int e, int k0, int n0,
                         uint16_t (*t)[72]) {
  const int r = threadIdx.x >> 2;          // 0..63
  const int c0 = (threadIdx.x & 3) * 16;   // 0,16,32,48
  const float* src = in + ((size_t)e * K + k0 + r) * N + n0 + c0;
#pragma unroll
  for (int q = 0; q < 4; ++q) {
    float4 v = *(const float4*)(src + q * 4);
    uint64_t pk = (uint64_t)f2b(v.x) | ((uint64_t)f2b(v.y) << 16) |
                  ((uint64_t)f2b(v.z) << 32) | ((uint64_t)f2b(v.w) << 48);
    *(uint64_t*)&t[r][c0 + q * 4] = pk;
  }
  __syncthreads();
  alignas(16) uint16_t buf[16];
#pragma unroll
  for (int j = 0; j < 16; ++j) buf[j] = t[c0 + j][r];
  uint16_t* dst = outp + ((size_t)e * N + n0 + r) * K + k0 + c0;
  *(uint4*)dst = *(const uint4*)&buf[0];
  *(uint4*)(dst + 8) = *(const uint4*)&buf[8];
}

// ------- K2: scan+scatter (block 0) || transpose W1 (blocks 1..8192) --------
// scan2 needs only gate output (prior kernel); trW1 needs only W1. Fusing
// them removes scan2's serial 5us from the critical path.
__global__ __launch_bounds__(256) void moe_k2(const int* __restrict__ gidx,
    const float* __restrict__ gw, int* __restrict__ meta,
    int* __restrict__ row_index, float* __restrict__ row_w,
    const float* __restrict__ W1, uint16_t* __restrict__ w1t) {
  __shared__ uint16_t t[64][72];
  __shared__ int cnt[8];
  __shared__ int offs[8];
  __shared__ int fill[8];
  const int bid = blockIdx.x;
  if (bid != 0) {
    int tt = bid - 1;                        // 8192 tiles: e(8) x kb(16) x nb(64)
    int e = tt >> 10, rem = tt & 1023;
    int kb = rem >> 6, nb2 = rem & 63;
    transpose_body(W1, w1t, 1024, 4096, e, kb * 64, nb2 * 64, t);
    return;
  }
  if (threadIdx.x < 8) { cnt[threadIdx.x] = 0; fill[threadIdx.x] = 0; }
  __syncthreads();
  int loc[8] = {0, 0, 0, 0, 0, 0, 0, 0};
  for (int i = threadIdx.x; i < 8192; i += 256) {
    int e = gidx[i];
#pragma unroll
    for (int q = 0; q < 8; ++q) loc[q] += (e == q) ? 1 : 0;
  }
#pragma unroll
  for (int q = 0; q < 8; ++q) if (loc[q]) atomicAdd(&cnt[q], loc[q]);
  __syncthreads();
  if (threadIdx.x == 0) {
    int off = 0, tIdx = 0;
    for (int e = 0; e < 8; ++e) {
      int c = cnt[e];
      meta[e] = c;
      meta[8 + e] = off;
      offs[e] = off;
      int nt = (c + 127) >> 7;
      for (int mt = 0; mt < nt; ++mt) {
        meta[32 + tIdx] = e;
        meta[104 + tIdx] = off + mt * 128;
        meta[176 + tIdx] = off + c;
        ++tIdx;
      }
      off += c;
    }
    meta[16] = off;
    meta[25] = tIdx;
  }
  __syncthreads();
  for (int i = threadIdx.x; i < 8192; i += 256) {
    int e = gidx[i];
    int pos = offs[e] + atomicAdd(&fill[e], 1);
    row_index[pos] = i >> 1;
    row_w[pos] = gw[i];
  }
}

// ---------------- GEMM core (r3/r11 structure, verified best) ---------------
// 128x128 tile, BK=32, 4 waves, 4 blocks/CU, double-buffered glds16 staging,
// conflict-free swizzle: LDS slot (row,ci) holds global k-chunk ci^((row>>1)&3).
// MODE 1: h[pos] = relu(gather(x)[pos] @ W1t[e]^T + b1[e]), ND=4096, KD=1024
// MODE 2: out[rix[pos]] += rw[pos]*(h[pos] @ W2t[e]^T + b2[e]), ND=1024, KD=4096
template <int KD, int ND, int MODE>
DEVI void gemm_core(int wg, const uint16_t* __restrict__ Am,
                    const uint16_t* __restrict__ Bt, const float* __restrict__ bias,
                    const int* __restrict__ meta, const int* __restrict__ row_index,
                    const float* __restrict__ row_w, uint16_t* __restrict__ hout,
                    float* __restrict__ out, uint16_t (*As)[4096], uint16_t (*Bs)[4096]) {
  constexpr int NB = ND / 128;
  constexpr int NIT = KD / 32;
  const int nb = wg % NB;
  const int ty = wg / NB;
  if (ty >= meta[25]) return;
  const int e = meta[32 + ty];
  const int pos0 = meta[104 + ty];
  const int vend = meta[176 + ty];

  const int tid = threadIdx.x;
  const int lane = tid & 63;
  const int w = tid >> 6;
  const int wr = w >> 1, wc = w & 1;

  size_t aoff[2], boff[2];
#pragma unroll
  for (int j = 0; j < 2; ++j) {
    int c = j * 256 + tid;
    int row = c >> 2;
    int skc = (c & 3) ^ ((row >> 1) & 3);
    int pos = pos0 + row;
    if (pos > 8191) pos = 8191;
    int ar = (MODE == 1) ? row_index[pos] : pos;
    aoff[j] = ((size_t)ar * KD + (size_t)skc * 8) * 2;
    boff[j] = (((size_t)e * ND + (size_t)nb * 128 + row) * KD + (size_t)skc * 8) * 2;
  }
  const char* Ag = (const char*)Am;
  const char* Bg = (const char*)Bt;

  f32x4_t acc[4][4];
  f32x4_t z;
  z[0] = 0.f; z[1] = 0.f; z[2] = 0.f; z[3] = 0.f;
#pragma unroll
  for (int m = 0; m < 4; ++m)
#pragma unroll
    for (int n = 0; n < 4; ++n) acc[m][n] = z;

  auto stage = [&](int buf, int t) {
#pragma unroll
    for (int j = 0; j < 2; ++j) {
      glds16(Ag + aoff[j] + (size_t)t * 64, &As[buf][(j * 256 + w * 64) * 8]);
      glds16(Bg + boff[j] + (size_t)t * 64, &Bs[buf][(j * 256 + w * 64) * 8]);
    }
  };

  stage(0, 0);
  __syncthreads();
  int cur = 0;
  for (int t = 0; t < NIT; ++t) {
    if (t + 1 < NIT) stage(cur ^ 1, t + 1);
    const uint16_t* Ap = As[cur];
    const uint16_t* Bp = Bs[cur];
    bf16x8_t af[4], bfr[4];
#pragma unroll
    for (int m = 0; m < 4; ++m) {
      int row = wr * 64 + m * 16 + (lane & 15);
      int skc = ((lane >> 4) ^ (row >> 1)) & 3;
      af[m] = *(const bf16x8_t*)(Ap + row * 32 + skc * 8);
    }
#pragma unroll
    for (int n = 0; n < 4; ++n) {
      int row = wc * 64 + n * 16 + (lane & 15);
      int skc = ((lane >> 4) ^ (row >> 1)) & 3;
      bfr[n] = *(const bf16x8_t*)(Bp + row * 32 + skc * 8);
    }
#pragma unroll
    for (int m = 0; m < 4; ++m)
#pragma unroll
      for (int n = 0; n < 4; ++n)
        acc[m][n] = __builtin_amdgcn_mfma_f32_16x16x32_bf16(af[m], bfr[n], acc[m][n], 0, 0, 0);
    __syncthreads();  // implicit vmcnt(0)+lgkmcnt(0) drains staged loads
    cur ^= 1;
  }

  // epilogue: C/D mapping col=lane&15, row=(lane>>4)*4+i
  const int cb = nb * 128 + wc * 64;
  if constexpr (MODE == 1) {
#pragma unroll
    for (int m = 0; m < 4; ++m) {
      int pr = pos0 + wr * 64 + m * 16 + ((lane >> 4) << 2);
#pragma unroll
      for (int i = 0; i < 4; ++i) {
        int pos = pr + i;
        if (pos < vend) {
#pragma unroll
          for (int n = 0; n < 4; ++n) {
            int col = cb + n * 16 + (lane & 15);
            float v = acc[m][n][i] + bias[e * ND + col];
            v = fmaxf(v, 0.f);
            hout[(size_t)pos * ND + col] = f2b(v);
          }
        }
      }
    }
  } else {
#pragma unroll
    for (int m = 0; m < 4; ++m) {
      int pr = pos0 + wr * 64 + m * 16 + ((lane >> 4) << 2);
#pragma unroll
      for (int i = 0; i < 4; ++i) {
        int pos = pr + i;
        if (pos < vend) {
          int bi = row_index[pos];
          float wgt = row_w[pos];
          float* orow = out + (size_t)bi * ND;
#pragma unroll
          for (int n = 0; n < 4; ++n) {
            int col = cb + n * 16 + (lane & 15);
            float v = (acc[m][n][i] + bias[e * ND + col]) * wgt;
            atomicAdd(orow + col, v);
          }
        }
      }
    }
  }
}

// ---------------- M2: GEMM1 (blocks 0..2303) || transpose W2 (2304..10495) --
__global__ __launch_bounds__(256, 4) void moe_m2(const uint16_t* __restrict__ xb,
    const uint16_t* __restrict__ w1t, const float* __restrict__ b1,
    const int* __restrict__ meta, const int* __restrict__ rix,
    const float* __restrict__ rw, uint16_t* __restrict__ h,
    const float* __restrict__ W2, uint16_t* __restrict__ w2t) {
  __shared__ uint16_t As[2][4096];
  __shared__ uint16_t Bs[2][4096];
  const int bid = blockIdx.x;
  if (bid < 2304) {
    // bijective XCD swizzle over the GEMM sub-grid (2304 % 8 == 0)
    constexpr int NWG = 2304;
    constexpr int Q8 = NWG >> 3;  // 288
    int wg = (bid & 7) * Q8 + (bid >> 3);
    gemm_core<1024, 4096, 1>(wg, xb, w1t, b1, meta, rix, rw, h, nullptr, As, Bs);
  } else {
    int tt = bid - 2304;                    // 8192 tiles: e(8) x kb(64) x nb(16)
    int e = tt >> 10, rem = tt & 1023;
    int kb = rem >> 4, nb2 = rem & 15;
    transpose_body(W2, w2t, 4096, 1024, e, kb * 64, nb2 * 64,
                   (uint16_t(*)[72]) & As[0][0]);
  }
}

// ---------------- GEMM2 standalone ------------------------------------------
__global__ __launch_bounds__(256, 4) void moe_gemm2(const uint16_t* __restrict__ h,
    const uint16_t* __restrict__ w2t, const float* __restrict__ b2,
    const int* __restrict__ meta, const int* __restrict__ rix,
    const float* __restrict__ rw, float* __restrict__ out) {
  __shared__ uint16_t As[2][4096];
  __shared__ uint16_t Bs[2][4096];
  const int nwg = gridDim.x;
  const int orig = blockIdx.x;
  const int q8 = nwg >> 3, r8 = nwg & 7, xcd = orig & 7, loc = orig >> 3;
  int wg = (xcd < r8 ? xcd * (q8 + 1) : r8 * (q8 + 1) + (xcd - r8) * q8) + loc;
  gemm_core<4096, 1024, 2>(wg, h, w2t, b2, meta, rix, rw, nullptr, out, As, Bs);
}

extern "C" void kernel_launch(void* const* d_in, const int* in_sizes, int n_in,
                              void* d_out, int out_size, void* d_ws, size_t ws_size,
                              hipStream_t stream) {
  const float* x  = (const float*)d_in[0];   // [4096,1024]
  const float* Wg = (const float*)d_in[1];   // [1024,8]
  const float* bg = (const float*)d_in[2];   // [8]
  const float* W1 = (const float*)d_in[3];   // [8,1024,4096]
  const float* b1 = (const float*)d_in[4];   // [8,4096]
  const float* W2 = (const float*)d_in[5];   // [8,4096,1024]
  const float* b2 = (const float*)d_in[6];   // [8,1024]
  float* out = (float*)d_out;                // [4096,1024]

  char* ws = (char*)d_ws;
  uint16_t* w1t = (uint16_t*)ws; ws += (size_t)8 * 4096 * 1024 * 2;  // [E][H][D] bf16
  uint16_t* w2t = (uint16_t*)ws; ws += (size_t)8 * 1024 * 4096 * 2;  // [E][O][H] bf16
  uint16_t* xb  = (uint16_t*)ws; ws += (size_t)4096 * 1024 * 2;      // [B][D] bf16
  uint16_t* h   = (uint16_t*)ws; ws += (size_t)8192 * 4096 * 2;      // [8192][H] bf16
  int*   gidx = (int*)ws;   ws += 8192 * 4;
  float* gw   = (float*)ws; ws += 8192 * 4;
  int*   rix  = (int*)ws;   ws += 8192 * 4;
  float* rw   = (float*)ws; ws += 8192 * 4;
  int*   meta = (int*)ws;   ws += 4096;

  hipMemsetAsync(d_out, 0, (size_t)4096 * 1024 * 4, stream);
  // K1: gate only (short critical path to scan)
  moe_gate<<<dim3(1024), 256, 0, stream>>>(x, Wg, bg, gidx, gw, xb);
  // K2: scan+scatter (1 block) || transpose W1 (8192)
  moe_k2<<<dim3(1 + 8192), 256, 0, stream>>>(gidx, gw, meta, rix, rw, W1, w1t);
  // M2: GEMM1 (2304) || transpose W2 (8192)
  moe_m2<<<dim3(2304 + 8192), 256, 0, stream>>>(xb, w1t, b1, meta, rix, rw, h, W2, w2t);
  // GEMM2: 8 nb * 72 ty = 576
  moe_gemm2<<<dim3(8 * MAXT), 256, 0, stream>>>(h, w2t, b2, meta, rix, rw, out);
}

// Round 14
// 387.374 us; speedup vs baseline: 1.0349x; 1.0065x over previous
//
#include <hip/hip_runtime.h>
#include <cstdint>

#define DEVI __device__ __forceinline__

typedef __bf16 bf16x8_t __attribute__((ext_vector_type(8)));
typedef float f32x4_t __attribute__((ext_vector_type(4)));

typedef const __attribute__((address_space(1))) unsigned int* gas_t;
typedef __attribute__((address_space(3))) unsigned int* las_t;

// async global->LDS, 16B per lane, dst = wave-uniform base (+lane*16 by HW)
DEVI void glds16(const void* g, void* l) {
  __builtin_amdgcn_global_load_lds((gas_t)g, (las_t)l, 16, 0, 0);
}

DEVI uint16_t f2b(float f) {  // fp32 -> bf16 RNE
  uint32_t u = __builtin_bit_cast(uint32_t, f);
  u += 0x7fffu + ((u >> 16) & 1u);
  return (uint16_t)(u >> 16);
}

// meta layout (ints): [0..7] counts, [8..16] offsets(9), [17..24] fill,
// [25] nTiles128, [32..103] tileExpert, [104..175] tilePos0, [176..247] tileValidEnd
static constexpr int MAXT = 72;

// ---------------- gate: logits + top2 + softmax + x->bf16 (fused cvt) -------
__global__ __launch_bounds__(256) void moe_gate(const float* __restrict__ x,
    const float* __restrict__ Wg, const float* __restrict__ bg,
    int* __restrict__ gidx, float* __restrict__ gw, uint16_t* __restrict__ xb) {
  const int lane = threadIdx.x & 63;
  const int b = blockIdx.x * 4 + (threadIdx.x >> 6);
  float acc[8];
#pragma unroll
  for (int e = 0; e < 8; ++e) acc[e] = 0.f;
  const float* xr = x + (size_t)b * 1024;
  uint16_t* xbr = xb + (size_t)b * 1024;
#pragma unroll
  for (int it = 0; it < 4; ++it) {
    const int d0 = it * 256 + lane * 4;
    float4 xv = *(const float4*)(xr + d0);
    uint64_t pk = (uint64_t)f2b(xv.x) | ((uint64_t)f2b(xv.y) << 16) |
                  ((uint64_t)f2b(xv.z) << 32) | ((uint64_t)f2b(xv.w) << 48);
    *(uint64_t*)(xbr + d0) = pk;
    float xs[4] = {xv.x, xv.y, xv.z, xv.w};
#pragma unroll
    for (int q = 0; q < 4; ++q) {
      const float4* wrow = (const float4*)(Wg + (size_t)(d0 + q) * 8);
      float4 wa = wrow[0], wb = wrow[1];
      acc[0] += xs[q] * wa.x; acc[1] += xs[q] * wa.y;
      acc[2] += xs[q] * wa.z; acc[3] += xs[q] * wa.w;
      acc[4] += xs[q] * wb.x; acc[5] += xs[q] * wb.y;
      acc[6] += xs[q] * wb.z; acc[7] += xs[q] * wb.w;
    }
  }
#pragma unroll
  for (int off = 32; off; off >>= 1)
#pragma unroll
    for (int e = 0; e < 8; ++e) acc[e] += __shfl_xor(acc[e], off, 64);
  if (lane == 0) {
    float l[8];
#pragma unroll
    for (int e = 0; e < 8; ++e) l[e] = acc[e] + bg[e];
    int i0 = 0;
#pragma unroll
    for (int e = 1; e < 8; ++e) if (l[e] > l[i0]) i0 = e;   // strict > : matches top_k tie rule
    int i1 = (i0 == 0) ? 1 : 0;
#pragma unroll
    for (int e = 0; e < 8; ++e) if (e != i0 && l[e] > l[i1]) i1 = e;
    float ex = expf(l[i1] - l[i0]);
    float s = 1.f + ex;
    gidx[2 * b] = i0; gidx[2 * b + 1] = i1;
    gw[2 * b] = 1.f / s; gw[2 * b + 1] = ex / s;
  }
}

// ---------------- transpose body: [E][K][N] fp32 -> [E][N][K] bf16 ----------
DEVI void transpose_body(const float* __restrict__ in, uint16_t* __restrict__ outp,
                         int K, int N, int e, int k0, int n0,
                         uint16_t (*t)[72]) {
  const int r = threadIdx.x >> 2;          // 0..63
  const int c0 = (threadIdx.x & 3) * 16;   // 0,16,32,48
  const float* src = in + ((size_t)e * K + k0 + r) * N + n0 + c0;
#pragma unroll
  for (int q = 0; q < 4; ++q) {
    float4 v = *(const float4*)(src + q * 4);
    uint64_t pk = (uint64_t)f2b(v.x) | ((uint64_t)f2b(v.y) << 16) |
                  ((uint64_t)f2b(v.z) << 32) | ((uint64_t)f2b(v.w) << 48);
    *(uint64_t*)&t[r][c0 + q * 4] = pk;
  }
  __syncthreads();
  alignas(16) uint16_t buf[16];
#pragma unroll
  for (int j = 0; j < 16; ++j) buf[j] = t[c0 + j][r];
  uint16_t* dst = outp + ((size_t)e * N + n0 + r) * K + k0 + c0;
  *(uint4*)dst = *(const uint4*)&buf[0];
  *(uint4*)(dst + 8) = *(const uint4*)&buf[8];
}

// ------- K2: scan+scatter (block 0) || transpose W1 + zero d_out (1..8192) --
// scan2 needs only gate output (prior kernel); trW1 needs only W1. The
// transpose blocks also zero d_out (2KB each, exact 16MB coverage) --
// replaces the serial hipMemsetAsync; stream order guarantees completion
// before GEMM2's atomics.
__global__ __launch_bounds__(256) void moe_k2(const int* __restrict__ gidx,
    const float* __restrict__ gw, int* __restrict__ meta,
    int* __restrict__ row_index, float* __restrict__ row_w,
    const float* __restrict__ W1, uint16_t* __restrict__ w1t,
    float4* __restrict__ out4) {
  __shared__ uint16_t t[64][72];
  __shared__ int cnt[8];
  __shared__ int offs[8];
  __shared__ int fill[8];
  const int bid = blockIdx.x;
  if (bid != 0) {
    int tt = bid - 1;                        // 8192 tiles: e(8) x kb(16) x nb(64)
    if (threadIdx.x < 128) {                 // zero 128 float4 = 2KB of d_out
      float4 z4; z4.x = 0.f; z4.y = 0.f; z4.z = 0.f; z4.w = 0.f;
      out4[(size_t)tt * 128 + threadIdx.x] = z4;
    }
    int e = tt >> 10, rem = tt & 1023;
    int kb = rem >> 6, nb2 = rem & 63;
    transpose_body(W1, w1t, 1024, 4096, e, kb * 64, nb2 * 64, t);
    return;
  }
  if (threadIdx.x < 8) { cnt[threadIdx.x] = 0; fill[threadIdx.x] = 0; }
  __syncthreads();
  int loc[8] = {0, 0, 0, 0, 0, 0, 0, 0};
  for (int i = threadIdx.x; i < 8192; i += 256) {
    int e = gidx[i];
#pragma unroll
    for (int q = 0; q < 8; ++q) loc[q] += (e == q) ? 1 : 0;
  }
#pragma unroll
  for (int q = 0; q < 8; ++q) if (loc[q]) atomicAdd(&cnt[q], loc[q]);
  __syncthreads();
  if (threadIdx.x == 0) {
    int off = 0, tIdx = 0;
    for (int e = 0; e < 8; ++e) {
      int c = cnt[e];
      meta[e] = c;
      meta[8 + e] = off;
      offs[e] = off;
      int nt = (c + 127) >> 7;
      for (int mt = 0; mt < nt; ++mt) {
        meta[32 + tIdx] = e;
        meta[104 + tIdx] = off + mt * 128;
        meta[176 + tIdx] = off + c;
        ++tIdx;
      }
      off += c;
    }
    meta[16] = off;
    meta[25] = tIdx;
  }
  __syncthreads();
  for (int i = threadIdx.x; i < 8192; i += 256) {
    int e = gidx[i];
    int pos = offs[e] + atomicAdd(&fill[e], 1);
    row_index[pos] = i >> 1;
    row_w[pos] = gw[i];
  }
}

// ---------------- GEMM core (r3/r11 structure, verified best) ---------------
// 128x128 tile, BK=32, 4 waves, 4 blocks/CU, double-buffered glds16 staging,
// conflict-free swizzle: LDS slot (row,ci) holds global k-chunk ci^((row>>1)&3).
// MODE 1: h[pos] = relu(gather(x)[pos] @ W1t[e]^T + b1[e]), ND=4096, KD=1024
// MODE 2: out[rix[pos]] += rw[pos]*(h[pos] @ W2t[e]^T + b2[e]), ND=1024, KD=4096
template <int KD, int ND, int MODE>
DEVI void gemm_core(int wg, const uint16_t* __restrict__ Am,
                    const uint16_t* __restrict__ Bt, const float* __restrict__ bias,
                    const int* __restrict__ meta, const int* __restrict__ row_index,
                    const float* __restrict__ row_w, uint16_t* __restrict__ hout,
                    float* __restrict__ out, uint16_t (*As)[4096], uint16_t (*Bs)[4096]) {
  constexpr int NB = ND / 128;
  constexpr int NIT = KD / 32;
  const int nb = wg % NB;
  const int ty = wg / NB;
  if (ty >= meta[25]) return;
  const int e = meta[32 + ty];
  const int pos0 = meta[104 + ty];
  const int vend = meta[176 + ty];

  const int tid = threadIdx.x;
  const int lane = tid & 63;
  const int w = tid >> 6;
  const int wr = w >> 1, wc = w & 1;

  size_t aoff[2], boff[2];
#pragma unroll
  for (int j = 0; j < 2; ++j) {
    int c = j * 256 + tid;
    int row = c >> 2;
    int skc = (c & 3) ^ ((row >> 1) & 3);
    int pos = pos0 + row;
    if (pos > 8191) pos = 8191;
    int ar = (MODE == 1) ? row_index[pos] : pos;
    aoff[j] = ((size_t)ar * KD + (size_t)skc * 8) * 2;
    boff[j] = (((size_t)e * ND + (size_t)nb * 128 + row) * KD + (size_t)skc * 8) * 2;
  }
  const char* Ag = (const char*)Am;
  const char* Bg = (const char*)Bt;

  f32x4_t acc[4][4];
  f32x4_t z;
  z[0] = 0.f; z[1] = 0.f; z[2] = 0.f; z[3] = 0.f;
#pragma unroll
  for (int m = 0; m < 4; ++m)
#pragma unroll
    for (int n = 0; n < 4; ++n) acc[m][n] = z;

  auto stage = [&](int buf, int t) {
#pragma unroll
    for (int j = 0; j < 2; ++j) {
      glds16(Ag + aoff[j] + (size_t)t * 64, &As[buf][(j * 256 + w * 64) * 8]);
      glds16(Bg + boff[j] + (size_t)t * 64, &Bs[buf][(j * 256 + w * 64) * 8]);
    }
  };

  stage(0, 0);
  __syncthreads();
  int cur = 0;
  for (int t = 0; t < NIT; ++t) {
    if (t + 1 < NIT) stage(cur ^ 1, t + 1);
    const uint16_t* Ap = As[cur];
    const uint16_t* Bp = Bs[cur];
    bf16x8_t af[4], bfr[4];
#pragma unroll
    for (int m = 0; m < 4; ++m) {
      int row = wr * 64 + m * 16 + (lane & 15);
      int skc = ((lane >> 4) ^ (row >> 1)) & 3;
      af[m] = *(const bf16x8_t*)(Ap + row * 32 + skc * 8);
    }
#pragma unroll
    for (int n = 0; n < 4; ++n) {
      int row = wc * 64 + n * 16 + (lane & 15);
      int skc = ((lane >> 4) ^ (row >> 1)) & 3;
      bfr[n] = *(const bf16x8_t*)(Bp + row * 32 + skc * 8);
    }
#pragma unroll
    for (int m = 0; m < 4; ++m)
#pragma unroll
      for (int n = 0; n < 4; ++n)
        acc[m][n] = __builtin_amdgcn_mfma_f32_16x16x32_bf16(af[m], bfr[n], acc[m][n], 0, 0, 0);
    __syncthreads();  // implicit vmcnt(0)+lgkmcnt(0) drains staged loads
    cur ^= 1;
  }

  // epilogue: C/D mapping col=lane&15, row=(lane>>4)*4+i
  const int cb = nb * 128 + wc * 64;
  if constexpr (MODE == 1) {
#pragma unroll
    for (int m = 0; m < 4; ++m) {
      int pr = pos0 + wr * 64 + m * 16 + ((lane >> 4) << 2);
#pragma unroll
      for (int i = 0; i < 4; ++i) {
        int pos = pr + i;
        if (pos < vend) {
#pragma unroll
          for (int n = 0; n < 4; ++n) {
            int col = cb + n * 16 + (lane & 15);
            float v = acc[m][n][i] + bias[e * ND + col];
            v = fmaxf(v, 0.f);
            hout[(size_t)pos * ND + col] = f2b(v);
          }
        }
      }
    }
  } else {
#pragma unroll
    for (int m = 0; m < 4; ++m) {
      int pr = pos0 + wr * 64 + m * 16 + ((lane >> 4) << 2);
#pragma unroll
      for (int i = 0; i < 4; ++i) {
        int pos = pr + i;
        if (pos < vend) {
          int bi = row_index[pos];
          float wgt = row_w[pos];
          float* orow = out + (size_t)bi * ND;
#pragma unroll
          for (int n = 0; n < 4; ++n) {
            int col = cb + n * 16 + (lane & 15);
            float v = (acc[m][n][i] + bias[e * ND + col]) * wgt;
            atomicAdd(orow + col, v);
          }
        }
      }
    }
  }
}

// ---------------- M2: GEMM1 (blocks 0..2303) || transpose W2 (2304..10495) --
__global__ __launch_bounds__(256, 4) void moe_m2(const uint16_t* __restrict__ xb,
    const uint16_t* __restrict__ w1t, const float* __restrict__ b1,
    const int* __restrict__ meta, const int* __restrict__ rix,
    const float* __restrict__ rw, uint16_t* __restrict__ h,
    const float* __restrict__ W2, uint16_t* __restrict__ w2t) {
  __shared__ uint16_t As[2][4096];
  __shared__ uint16_t Bs[2][4096];
  const int bid = blockIdx.x;
  if (bid < 2304) {
    // bijective XCD swizzle over the GEMM sub-grid (2304 % 8 == 0)
    constexpr int NWG = 2304;
    constexpr int Q8 = NWG >> 3;  // 288
    int wg = (bid & 7) * Q8 + (bid >> 3);
    gemm_core<1024, 4096, 1>(wg, xb, w1t, b1, meta, rix, rw, h, nullptr, As, Bs);
  } else {
    int tt = bid - 2304;                    // 8192 tiles: e(8) x kb(64) x nb(16)
    int e = tt >> 10, rem = tt & 1023;
    int kb = rem >> 4, nb2 = rem & 15;
    transpose_body(W2, w2t, 4096, 1024, e, kb * 64, nb2 * 64,
                   (uint16_t(*)[72]) & As[0][0]);
  }
}

// ---------------- GEMM2 standalone ------------------------------------------
__global__ __launch_bounds__(256, 4) void moe_gemm2(const uint16_t* __restrict__ h,
    const uint16_t* __restrict__ w2t, const float* __restrict__ b2,
    const int* __restrict__ meta, const int* __restrict__ rix,
    const float* __restrict__ rw, float* __restrict__ out) {
  __shared__ uint16_t As[2][4096];
  __shared__ uint16_t Bs[2][4096];
  const int nwg = gridDim.x;
  const int orig = blockIdx.x;
  const int q8 = nwg >> 3, r8 = nwg & 7, xcd = orig & 7, loc = orig >> 3;
  int wg = (xcd < r8 ? xcd * (q8 + 1) : r8 * (q8 + 1) + (xcd - r8) * q8) + loc;
  gemm_core<4096, 1024, 2>(wg, h, w2t, b2, meta, rix, rw, nullptr, out, As, Bs);
}

extern "C" void kernel_launch(void* const* d_in, const int* in_sizes, int n_in,
                              void* d_out, int out_size, void* d_ws, size_t ws_size,
                              hipStream_t stream) {
  const float* x  = (const float*)d_in[0];   // [4096,1024]
  const float* Wg = (const float*)d_in[1];   // [1024,8]
  const float* bg = (const float*)d_in[2];   // [8]
  const float* W1 = (const float*)d_in[3];   // [8,1024,4096]
  const float* b1 = (const float*)d_in[4];   // [8,4096]
  const float* W2 = (const float*)d_in[5];   // [8,4096,1024]
  const float* b2 = (const float*)d_in[6];   // [8,1024]
  float* out = (float*)d_out;                // [4096,1024]

  char* ws = (char*)d_ws;
  uint16_t* w1t = (uint16_t*)ws; ws += (size_t)8 * 4096 * 1024 * 2;  // [E][H][D] bf16
  uint16_t* w2t = (uint16_t*)ws; ws += (size_t)8 * 1024 * 4096 * 2;  // [E][O][H] bf16
  uint16_t* xb  = (uint16_t*)ws; ws += (size_t)4096 * 1024 * 2;      // [B][D] bf16
  uint16_t* h   = (uint16_t*)ws; ws += (size_t)8192 * 4096 * 2;      // [8192][H] bf16
  int*   gidx = (int*)ws;   ws += 8192 * 4;
  float* gw   = (float*)ws; ws += 8192 * 4;
  int*   rix  = (int*)ws;   ws += 8192 * 4;
  float* rw   = (float*)ws; ws += 8192 * 4;
  int*   meta = (int*)ws;   ws += 4096;

  // K1: gate only (short critical path to scan)
  moe_gate<<<dim3(1024), 256, 0, stream>>>(x, Wg, bg, gidx, gw, xb);
  // K2: scan+scatter (1 block) || transpose W1 + d_out zeroing (8192)
  moe_k2<<<dim3(1 + 8192), 256, 0, stream>>>(gidx, gw, meta, rix, rw, W1, w1t,
                                             (float4*)out);
  // M2: GEMM1 (2304) || transpose W2 (8192)
  moe_m2<<<dim3(2304 + 8192), 256, 0, stream>>>(xb, w1t, b1, meta, rix, rw, h, W2, w2t);
  // GEMM2: 8 nb * 72 ty = 576
  moe_gemm2<<<dim3(8 * MAXT), 256, 0, stream>>>(h, w2t, b2, meta, rix, rw, out);
}